// Round 6
// baseline (351.135 us; speedup 1.0000x reference)
//
#include <hip/hip_runtime.h>
#include <hip/hip_bf16.h>

typedef float f4v __attribute__((ext_vector_type(4)));
typedef short s8v __attribute__((ext_vector_type(8)));

#define TT 128
#define II 28
#define HH 200
#define BB 16     // batch rows per block
#define NT 128    // 2 waves per block
#define SH 232    // Hs row stride (bf16): 464 B rows, 16B-aligned
#define KX 224    // combined-K offset of the x block (kc7 = K 224..255)
#define SF 212    // Hf row stride (fp32)

// pack 2 f32 -> 2 bf16 (RNE) in one dword (v_cvt_pk_bf16_f32)
__device__ __forceinline__ int pk_bf16(float a, float b) {
    union { __hip_bfloat162 h; int i; } u;
    u.h = __float22bfloat162_rn(make_float2(a, b));
    return u.i;
}
__device__ __forceinline__ short f2bf(float f) {
    union { __hip_bfloat16 h; short s; } u;
    u.h = __float2bfloat16(f);
    return u.s;
}

__global__ __launch_bounds__(NT, 1)
void rnn_w3(const float* __restrict__ x,
            const float* __restrict__ W_ih,
            const float* __restrict__ W_hh,
            const float* __restrict__ b_ih,
            const float* __restrict__ b_hh,
            const float* __restrict__ W_fc,
            const float* __restrict__ b_fc,
            float* __restrict__ out)
{
    // LDS: Hs 2*16*232*2 = 14848 B + Hf 16*212*4 = 13568 B => 28.4 KB
    __shared__ __align__(16) short Hs[2][BB][SH]; // bf16 h: cols 0..199, pad 200..231 = 0
    __shared__ __align__(16) float Hf[BB][SF];    // final h fp32 for FC

    const int tid  = threadIdx.x;
    const int lane = tid & 63;
    const int q    = lane >> 4;   // quad 0..3
    const int lr   = lane & 15;   // A: j-in-tile ; B/C: batch row
    const int wave = tid >> 6;    // 0..1
    const int b0   = blockIdx.x * BB;

    // j-tiles: wave0 -> jt 0..6, wave1 -> jt 7..12 (+ one dummy zero tile)
    const int first = wave * 7;

    // zero both h buffers (h0 = 0, pads = 0)
    for (int i = tid; i < 2 * BB * SH / 2; i += NT) ((int*)Hs)[i] = 0;

    // ---- W~ fragments resident in registers ----
    // A-frag(u,kc): lane holds W~[j=16*(first+u)+lr][k=32*kc+8*q+i], i=0..7
    // W~[j][k] = W_hh[j][k] (k<200) | W_ih[j][k-224] (224<=k<252) | 0
    // wave1 u=6 -> j>=208 -> all zero (dummy tile, MFMA result discarded)
    s8v Af[7][8];
    #pragma unroll
    for (int u = 0; u < 7; ++u) {
        const int j = 16 * (first + u) + lr;
        #pragma unroll
        for (int kc = 0; kc < 8; ++kc) {
            union { short s[8]; s8v v; } tv;
            #pragma unroll
            for (int i = 0; i < 8; ++i) {
                const int k = 32 * kc + 8 * q + i;
                float w = 0.0f;
                if (j < HH) {
                    if (k < HH)                    w = W_hh[j * HH + k];
                    else if (k >= KX && k < KX+II) w = W_ih[j * II + (k - KX)];
                }
                tv.s[i] = f2bf(w);
            }
            Af[u][kc] = tv.v;
        }
    }

    // per-lane bias as MFMA C-init (C rows j = 16*jt + 4*q + i)
    f4v biasv[7];
    #pragma unroll
    for (int u = 0; u < 7; ++u) {
        f4v bv = {0.f, 0.f, 0.f, 0.f};
        #pragma unroll
        for (int i = 0; i < 4; ++i) {
            const int j = 16 * (first + u) + 4 * q + i;
            if (j < HH) bv[i] = b_ih[j] + b_hh[j];
        }
        biasv[u] = bv;
    }

    // ---- x chunk pipeline: lane (lr,q) holds x[b0+lr][t][8q..8q+7] ----
    const float* xp = x + (long)(b0 + lr) * (TT * II) + 8 * q;
    f4v xA[8] = {}, xB[8] = {};   // 4 steps per buffer; [2s]=cols 8q..8q+3, [2s+1]=8q+4..8q+7
    #pragma unroll
    for (int s = 0; s < 4; ++s) {
        xA[2*s] = *(const f4v*)(xp + s * II);
        if (q < 3) xA[2*s+1] = *(const f4v*)(xp + s * II + 4);
        // q==3: slots map to K 252..255 where W~ = 0; stale/zero values are harmless
    }

    __syncthreads();   // zeroed Hs visible

    auto step = [&](int t, int pb, const f4v& xa, const f4v& xb) {
        // ds_reads first: latency overlaps the x-cvt VALU below
        s8v bf[7];
        #pragma unroll
        for (int kc = 0; kc < 7; ++kc)
            bf[kc] = *(const s8v*)&Hs[pb][lr][32 * kc + 8 * q];

        union { int i4[4]; s8v v; } xf;
        xf.i4[0] = pk_bf16(xa.x, xa.y);
        xf.i4[1] = pk_bf16(xa.z, xa.w);
        xf.i4[2] = pk_bf16(xb.x, xb.y);
        xf.i4[3] = pk_bf16(xb.z, xb.w);

        // x-chunk MFMAs first (register-fed, C = bias), then kc-outer/u-inner:
        // dependent distance 7 within each acc chain -> latency hidden
        f4v acc[7];
        #pragma unroll
        for (int u = 0; u < 7; ++u)
            acc[u] = __builtin_amdgcn_mfma_f32_16x16x32_bf16(Af[u][7], xf.v, biasv[u], 0, 0, 0);
        #pragma unroll
        for (int kc = 0; kc < 7; ++kc) {
            #pragma unroll
            for (int u = 0; u < 7; ++u)
                acc[u] = __builtin_amdgcn_mfma_f32_16x16x32_bf16(Af[u][kc], bf[kc], acc[u], 0, 0, 0);
        }

        // retire: relu -> bf16 -> Hs[pb^1]; wave1's u==6 is the dummy tile
        #pragma unroll
        for (int u = 0; u < 7; ++u) {
            if (u < 6 || wave == 0) {
                const int jt = first + u;
                const float r0 = fmaxf(acc[u].x, 0.f), r1 = fmaxf(acc[u].y, 0.f);
                const float r2 = fmaxf(acc[u].z, 0.f), r3 = fmaxf(acc[u].w, 0.f);
                int2 hv;
                hv.x = pk_bf16(r0, r1);
                hv.y = pk_bf16(r2, r3);
                *(int2*)&Hs[pb ^ 1][lr][16 * jt + 4 * q] = hv;
                if (t == TT - 1) {
                    f4v rf = {r0, r1, r2, r3};
                    *(f4v*)&Hf[lr][16 * jt + 4 * q] = rf;
                }
            }
        }
        __syncthreads();   // one barrier per step
    };

    // chunk = 4 steps; loads for the NEXT chunk issue right after a barrier,
    // so only the first step-barrier of each chunk drains a real vmcnt.
    auto chunk = [&](int tc, f4v (&cur)[8], f4v (&nxt)[8]) {
        if (tc + 4 < TT) {
            #pragma unroll
            for (int s = 0; s < 4; ++s) {
                nxt[2*s] = *(const f4v*)(xp + (tc + 4 + s) * II);
                if (q < 3) nxt[2*s+1] = *(const f4v*)(xp + (tc + 4 + s) * II + 4);
            }
        }
        #pragma unroll
        for (int s = 0; s < 4; ++s)
            step(tc + s, (tc + s) & 1, cur[2*s], cur[2*s+1]);
    };

    for (int tc = 0; tc < TT; tc += 8) {
        chunk(tc,     xA, xB);
        chunk(tc + 4, xB, xA);
    }

    // ---- FC epilogue (fp32): out[b][o] = h_T . W_fc[o] + b_fc[o] ----
    for (int i = tid; i < BB * 10; i += NT) {
        const int o = i >> 4, r = i & 15;
        float s = b_fc[o];
        for (int k = 0; k < HH; ++k)
            s = fmaf(Hf[r][k], W_fc[o * HH + k], s);
        __builtin_nontemporal_store(s, &out[(long)(b0 + r) * 10 + o]);
    }
}

extern "C" void kernel_launch(void* const* d_in, const int* in_sizes, int n_in,
                              void* d_out, int out_size, void* d_ws, size_t ws_size,
                              hipStream_t stream) {
    const float* x    = (const float*)d_in[0];
    const float* W_ih = (const float*)d_in[1];
    const float* W_hh = (const float*)d_in[2];
    const float* b_ih = (const float*)d_in[3];
    const float* b_hh = (const float*)d_in[4];
    const float* W_fc = (const float*)d_in[5];
    const float* b_fc = (const float*)d_in[6];
    float* out = (float*)d_out;

    rnn_w3<<<dim3(8192 / BB), dim3(NT), 0, stream>>>(
        x, W_ih, W_hh, b_ih, b_hh, W_fc, b_fc, out);
}

// Round 7
// 302.327 us; speedup vs baseline: 1.1614x; 1.1614x over previous
//
#include <hip/hip_runtime.h>

typedef float f4v __attribute__((ext_vector_type(4)));
typedef float f2v __attribute__((ext_vector_type(2)));
typedef short s8v __attribute__((ext_vector_type(8)));

#define TT 128
#define II 28
#define HH 200
#define BB 16        // batch rows per block
#define NT 256       // 4 waves
#define SH 232       // Hs row stride (bf16): 464 B, 16B-aligned rows
#define KX 224       // combined-K offset of the x block (kc7 = K 224..255)
#define CH 8         // timesteps per x chunk
#define XW (CH * BB * II)   // 3584 f32 per chunk buffer

// round-half-up f32->bf16 for a pair, packed to one dword: 2 adds + 1 v_perm
__device__ __forceinline__ unsigned pk_hu(float a, float b) {
    unsigned ua = __builtin_bit_cast(unsigned, a) + 0x8000u;
    unsigned ub = __builtin_bit_cast(unsigned, b) + 0x8000u;
    // result = (hi16(ub) << 16) | hi16(ua)
    return __builtin_amdgcn_perm(ub, ua, 0x07060302);
}
__device__ __forceinline__ short f2bf(float f) {
    return (short)((__builtin_bit_cast(unsigned, f) + 0x8000u) >> 16);
}

__global__ __launch_bounds__(NT, 2)
void rnn_r7(const float* __restrict__ x,
            const float* __restrict__ W_ih,
            const float* __restrict__ W_hh,
            const float* __restrict__ b_ih,
            const float* __restrict__ b_hh,
            const float* __restrict__ W_fc,
            const float* __restrict__ b_fc,
            float* __restrict__ out)
{
    // LDS: Hs 2*16*232*2 = 14848 B + Xl 2*(3584+8)*4 = 28736 B  => ~42.6 KB -> 2 blocks/CU
    __shared__ __align__(16) short Hs[2][BB][SH]; // bf16 h: cols 0..199, pad 200..231 = 0
    __shared__ __align__(16) float Xl[2][XW + 8]; // raw f32 x, [t][r][c] contiguous (+pad for q=3 overread)

    const int tid  = threadIdx.x;
    const int lane = tid & 63;
    const int q    = lane >> 4;   // quad 0..3
    const int lr   = lane & 15;   // A: j-in-tile ; B/C: batch row
    const int wave = tid >> 6;    // 0..3
    const int b0   = blockIdx.x * BB;

    // j-tile split {4,3,3,3} over 13 tiles
    const int first = (wave == 0) ? 0 : 1 + 3 * wave;
    const int cnt   = (wave == 0) ? 4 : 3;

    // zero both h buffers (h0 = 0, pads = 0)
    for (int i = tid; i < 2 * BB * SH / 2; i += NT) ((int*)Hs)[i] = 0;

    // ---- W~ fragments resident (AGPR-backed): A-frag(u,kc): W~[16*(first+u)+lr][32*kc+8*q+i]
    // W~[j][k] = W_hh[j][k] (k<200) | W_ih[j][k-224] (224<=k<252) | 0
    s8v Af[4][8];
    #pragma unroll
    for (int u = 0; u < 4; ++u) {
        const int j = 16 * (first + u) + lr;
        #pragma unroll
        for (int kc = 0; kc < 8; ++kc) {
            union { short s[8]; s8v v; } tv;
            #pragma unroll
            for (int i = 0; i < 8; ++i) {
                const int k = 32 * kc + 8 * q + i;
                float w = 0.0f;
                if (u < cnt && j < HH) {
                    if (k < HH)                    w = W_hh[j * HH + k];
                    else if (k >= KX && k < KX+II) w = W_ih[j * II + (k - KX)];
                }
                tv.s[i] = f2bf(w);
            }
            Af[u][kc] = tv.v;
        }
    }

    // per-lane bias as MFMA C-init (C rows j = 16*jt + 4*q + i)
    f4v biasv[4];
    #pragma unroll
    for (int u = 0; u < 4; ++u) {
        f4v bv = {0.f, 0.f, 0.f, 0.f};
        #pragma unroll
        for (int i = 0; i < 4; ++i) {
            const int j = 16 * (first + u) + 4 * q + i;
            if (u < cnt && j < HH) bv[i] = b_ih[j] + b_hh[j];
        }
        biasv[u] = bv;
    }

    // ---- x DMA precompute (waves 2,3 own the 14 global_load_lds issues per chunk) ----
    // linear 16B-chunk index m = ((wave-2)*7+e)*64 + lane ; m -> (t_loc, r, c4)
    const int wv = wave - 2;
    long xoff[7];
    #pragma unroll
    for (int e = 0; e < 7; ++e) {
        if (wv >= 0) {
            const int m  = ((wv * 7 + e) << 6) + lane;
            const int tl = m / 112;
            const int rm = m - tl * 112;
            const int r  = rm / 7;
            const int c4 = rm - r * 7;
            xoff[e] = ((long)(b0 + r) * TT + tl) * II + c4 * 4;
        } else xoff[e] = 0;
    }
    auto load_chunk = [&](int cc) {   // stage steps cc*8..cc*8+7 into Xl[cc&1]
        if (wv >= 0) {
            float* dbase = &Xl[cc & 1][(wv * 7) * 256];
            #pragma unroll
            for (int e = 0; e < 7; ++e) {
                const float* src = x + xoff[e] + (long)cc * (CH * II);
                __builtin_amdgcn_global_load_lds(
                    (const __attribute__((address_space(1))) void*)src,
                    (__attribute__((address_space(3))) void*)(dbase + e * 256),
                    16, 0, 0);
            }
        }
    };

    load_chunk(0);
    __syncthreads();   // drains DMA (vmcnt) + zeroed Hs visible

    for (int c = 0; c < TT / CH; ++c) {
        if (c + 1 < TT / CH) load_chunk(c + 1);   // in flight; drained by step-0's barrier
        #pragma unroll
        for (int s = 0; s < CH; ++s) {
            const int t  = c * CH + s;
            const int pb = t & 1;

            // h B-frags first (latency overlaps x cvt below)
            s8v bf[7];
            #pragma unroll
            for (int kc = 0; kc < 7; ++kc)
                bf[kc] = *(const s8v*)&Hs[pb][lr][32 * kc + 8 * q];

            // x from LDS f32 -> bf16 frag (lane q covers cols 8q..8q+7; q=3 tail cols >=28 hit
            // finite neighbor floats x 0-weights -> contribute 0)
            const float* xr = &Xl[c & 1][s * (BB * II) + lr * II + 8 * q];
            const f2v x0 = *(const f2v*)(xr + 0);
            const f2v x1 = *(const f2v*)(xr + 2);
            const f2v x2 = *(const f2v*)(xr + 4);
            const f2v x3 = *(const f2v*)(xr + 6);
            union { unsigned u4[4]; s8v v; } xf;
            xf.u4[0] = pk_hu(x0.x, x0.y);
            xf.u4[1] = pk_hu(x1.x, x1.y);
            xf.u4[2] = pk_hu(x2.x, x2.y);
            xf.u4[3] = pk_hu(x3.x, x3.y);

            // x-chunk MFMAs first (register-fed, C = bias), then kc-outer/u-inner (dep dist 4)
            f4v acc[4];
            #pragma unroll
            for (int u = 0; u < 4; ++u)
                if (u < cnt)
                    acc[u] = __builtin_amdgcn_mfma_f32_16x16x32_bf16(Af[u][7], xf.v, biasv[u], 0, 0, 0);
            #pragma unroll
            for (int kc = 0; kc < 7; ++kc) {
                #pragma unroll
                for (int u = 0; u < 4; ++u)
                    if (u < cnt)
                        acc[u] = __builtin_amdgcn_mfma_f32_16x16x32_bf16(Af[u][kc], bf[kc], acc[u], 0, 0, 0);
            }

            // retire: relu -> bf16(half-up) -> Hs[pb^1]
            #pragma unroll
            for (int u = 0; u < 4; ++u) {
                if (u < cnt) {
                    const int jt = first + u;
                    const float r0 = fmaxf(acc[u].x, 0.f), r1 = fmaxf(acc[u].y, 0.f);
                    const float r2 = fmaxf(acc[u].z, 0.f), r3 = fmaxf(acc[u].w, 0.f);
                    int2 hv;
                    hv.x = (int)pk_hu(r0, r1);
                    hv.y = (int)pk_hu(r2, r3);
                    *(int2*)&Hs[pb ^ 1][lr][16 * jt + 4 * q] = hv;
                }
            }
            __syncthreads();   // one barrier per step
        }
    }

    // ---- FC epilogue: h_T is bf16 in Hs[0] (t=127 wrote pb^1 = 0) ----
    if (tid < BB * 10) {
        const int o = tid >> 4, r = tid & 15;
        float sacc = b_fc[o];
        for (int k = 0; k < HH; ++k) {
            const float hk = __builtin_bit_cast(float,
                (unsigned)((unsigned short)Hs[0][r][k]) << 16);
            sacc = fmaf(hk, W_fc[o * HH + k], sacc);
        }
        __builtin_nontemporal_store(sacc, &out[(long)(b0 + r) * 10 + o]);
    }
}

extern "C" void kernel_launch(void* const* d_in, const int* in_sizes, int n_in,
                              void* d_out, int out_size, void* d_ws, size_t ws_size,
                              hipStream_t stream) {
    const float* x    = (const float*)d_in[0];
    const float* W_ih = (const float*)d_in[1];
    const float* W_hh = (const float*)d_in[2];
    const float* b_ih = (const float*)d_in[3];
    const float* b_hh = (const float*)d_in[4];
    const float* W_fc = (const float*)d_in[5];
    const float* b_fc = (const float*)d_in[6];
    float* out = (float*)d_out;

    rnn_r7<<<dim3(8192 / BB), dim3(NT), 0, stream>>>(
        x, W_ih, W_hh, b_ih, b_hh, W_fc, b_fc, out);
}